// Round 10
// baseline (36.199 us; speedup 1.0000x reference)
//
#include <hip/hip_runtime.h>
#include <math.h>

#define KG_B    16384
#define KG_D    128
#define KG_NR   24
#define KG_TM   32                        // elements per block
#define KG_BPAD (KG_B + KG_NR * KG_TM)    // 17152
#define KG_NGRP (KG_BPAD / KG_TM)         // 536

// ws layout: int perm[KG_BPAD] (bytes 0..68608)
//            | u64 acc @ byte 68608 | u32 done @ byte 68616
//            | ushort preW[24*16384] @ byte 131072
#define WS_ACC_BYTES  68608
#define WS_DONE_BYTES 68616
#define WS_PREW_BYTES 131072
#define KG_SCALE      1099511627776.0     // 2^40

typedef __attribute__((ext_vector_type(8))) short bf16x8;
typedef __attribute__((ext_vector_type(4))) float f32x4;

__device__ __forceinline__ unsigned bf16r(float f) {
    return (__float_as_uint(f) + 0x8000u) >> 16;
}
__device__ __forceinline__ unsigned pack2(float lo, float hi) {
    return bf16r(lo) | (bf16r(hi) << 16);
}

// ---- K1: block 0 = fused relation sort (+ acc/done reset);
//      blocks 1..24 = W^T bf16 prep, PLAIN col-major:
//      preW[k][col*128 + e] = bf16(W[k][e][col]). ----
__global__ __launch_bounds__(1024) void kg_sort_prep(const int* __restrict__ r,
                                                     const float* __restrict__ M,
                                                     int* __restrict__ perm,
                                                     unsigned long long* __restrict__ acc,
                                                     unsigned int* __restrict__ done,
                                                     unsigned short* __restrict__ preW) {
    __shared__ int cntw[16][25];
    __shared__ int basew[16][25];
    __shared__ int pbase_s[24];
    __shared__ int cnt_tot[24];
    __shared__ int total_s;
    __shared__ __align__(16) unsigned short sWp[KG_D * KG_D];   // 32 KB (prep path)

    const int t = threadIdx.x;

    if (blockIdx.x != 0) {
        // ---------- prep path: transpose+pack one 128x128 matrix ----------
        const int k  = blockIdx.x - 1;
        const int e  = t >> 3;              // 0..127
        const int c0 = (t & 7) * 16;
        const float* src = M + ((size_t)k << 14) + (size_t)e * KG_D + c0;
        float4 rw[4];
#pragma unroll
        for (int f = 0; f < 4; ++f) rw[f] = ((const float4*)src)[f];
#pragma unroll
        for (int dc = 0; dc < 16; ++dc) {
            const int col = c0 + dc;
            const float v = ((const float*)&rw[0])[dc];
            sWp[col * KG_D + e] = (unsigned short)bf16r(v);
        }
        __syncthreads();
        uint4* dst = (uint4*)(preW + ((size_t)k << 14));
        const uint4* s4 = (const uint4*)sWp;
        dst[2 * t]     = s4[2 * t];
        dst[2 * t + 1] = s4[2 * t + 1];
        return;
    }

    // ---------- sort path (single block) ----------
    if (t == 0) { *acc = 0ull; *done = 0u; }   // reset per call (flushed at kernel end)

    const int w = t >> 6;
    int* cz = &cntw[0][0];
    for (int i = t; i < 16 * 25; i += 1024) cz[i] = 0;
    __syncthreads();

    int kt[16];
#pragma unroll
    for (int j = 0; j < 16; ++j) kt[j] = r[j * 1024 + t];
#pragma unroll
    for (int j = 0; j < 16; ++j) atomicAdd(&cntw[w][kt[j]], 1);
    __syncthreads();

    if (t < 24) {
        int s = 0;
        for (int w2 = 0; w2 < 16; ++w2) { basew[w2][t] = s; s += cntw[w2][t]; }
        cnt_tot[t] = s;
    }
    __syncthreads();
    if (t == 0) {
        int run = 0;
        for (int k = 0; k < 24; ++k) {
            pbase_s[k] = run;
            run += (cnt_tot[k] + (KG_TM - 1)) & ~(KG_TM - 1);
        }
        total_s = run;
    }
    __syncthreads();
    if (t < 24)
        for (int w2 = 0; w2 < 16; ++w2) basew[w2][t] += pbase_s[t];
    for (int i = t; i < 16 * 25; i += 1024) cz[i] = 0;   // reuse cntw as cur
    __syncthreads();

#pragma unroll
    for (int j = 0; j < 16; ++j) {
        const int k = kt[j];
        const int pos = basew[w][k] + atomicAdd(&cntw[w][k], 1);
        perm[pos] = j * 1024 + t;
    }
    __syncthreads();

    if (t < 24) {
        const int e0 = pbase_s[t] + cnt_tot[t];
        const int e1 = pbase_s[t] + ((cnt_tot[t] + (KG_TM - 1)) & ~(KG_TM - 1));
        for (int p = e0; p < e1; ++p) perm[p] = -1;
    }
    for (int i = total_s + t; i < KG_BPAD; i += 1024) perm[i] = -1;
}

// ---- K2: MFMA main + fenceless deterministic finalize.
//      Block = 32 same-relation elements, 4 waves (rt=w&1 rows, chs=w>>1 cols).
//      X staged in LDS (R7/R9-verified); B direct from L2-resident preW. ----
__global__ __launch_bounds__(256, 4) void kg_main(
    const float* __restrict__ ent, const float* __restrict__ rel,
    const unsigned short* __restrict__ preW,
    const int* __restrict__ h,     const int* __restrict__ r,
    const int* __restrict__ pt,    const int* __restrict__ nt,
    const int* __restrict__ perm,
    unsigned long long* __restrict__ acc,
    unsigned int* __restrict__ done,
    float* __restrict__ out)
{
    __shared__ __align__(16) unsigned short sX[3 * KG_TM * KG_D];   // 24 KB
    __shared__ float sScr[2][KG_TM][4];

    const int tid   = threadIdx.x;
    const int slot0 = blockIdx.x * KG_TM;
    const int p0    = perm[slot0];

    float bs = 0.f;                       // block sum (valid at tid==0)

    if (p0 >= 0) {                        // uniform branch per block
        const int rb = __builtin_amdgcn_readfirstlane(r[p0]);

        // ---- stage X: thread t -> row g=t>>3, 16 dims at e0=(t&7)*16 ----
        {
            const int g  = tid >> 3;
            const int e0 = (tid & 7) * 16;
            const int pg = perm[slot0 + g];
            const int bb = pg < 0 ? p0 : pg;
            const int idx3[3] = { h[bb], pt[bb], nt[bb] };
            const int sw = (g & 7) << 3;
#pragma unroll
            for (int t3 = 0; t3 < 3; ++t3) {
                const float* src = ent + (size_t)idx3[t3] * KG_D + e0;
                const float4 f0 = ((const float4*)src)[0];
                const float4 f1 = ((const float4*)src)[1];
                const float4 f2 = ((const float4*)src)[2];
                const float4 f3 = ((const float4*)src)[3];
                uint4 u0, u1;
                u0.x = pack2(f0.x, f0.y); u0.y = pack2(f0.z, f0.w);
                u0.z = pack2(f1.x, f1.y); u0.w = pack2(f1.z, f1.w);
                u1.x = pack2(f2.x, f2.y); u1.y = pack2(f2.z, f2.w);
                u1.z = pack2(f3.x, f3.y); u1.w = pack2(f3.z, f3.w);
                unsigned short* base = sX + t3 * (KG_TM * KG_D) + g * KG_D;
                *(uint4*)(base + ((e0    ) ^ sw)) = u0;
                *(uint4*)(base + ((e0 + 8) ^ sw)) = u1;
            }
        }
        __syncthreads();

        const int l   = tid & 63;
        const int w   = tid >> 6;
        const int rt  = w & 1;
        const int chs = w >> 1;
        const int li  = l & 15;
        const int kq  = l >> 4;

        const int ar  = rt * 16 + li;
        const int asw = (ar & 7) << 3;

        const unsigned short* __restrict__ preWk = preW + ((size_t)rb << 14);

        f32x4 accf[3][4];
#pragma unroll
        for (int t3 = 0; t3 < 3; ++t3)
#pragma unroll
            for (int n = 0; n < 4; ++n) accf[t3][n] = (f32x4)0.f;

#pragma unroll
        for (int kk = 0; kk < 4; ++kk) {
            const int e0 = kk * 32 + kq * 8;
            bf16x8 af[3];
#pragma unroll
            for (int t3 = 0; t3 < 3; ++t3)
                af[t3] = *(const bf16x8*)&sX[t3 * (KG_TM * KG_D) + ar * KG_D + (e0 ^ asw)];
#pragma unroll
            for (int n = 0; n < 4; ++n) {
                const int col = chs * 64 + n * 16 + li;
                const bf16x8 bfr = *(const bf16x8*)&preWk[col * KG_D + e0];
                accf[0][n] = __builtin_amdgcn_mfma_f32_16x16x32_bf16(af[0], bfr, accf[0][n], 0, 0, 0);
                accf[1][n] = __builtin_amdgcn_mfma_f32_16x16x32_bf16(af[1], bfr, accf[1][n], 0, 0, 0);
                accf[2][n] = __builtin_amdgcn_mfma_f32_16x16x32_bf16(af[2], bfr, accf[2][n], 0, 0, 0);
            }
        }

        // ---- epilogue: C/D layout col=lane&15, row=(lane>>4)*4+reg ----
        float ps[4] = {0,0,0,0}, ns[4] = {0,0,0,0}, sq[4] = {0,0,0,0};
        const float* relrow = rel + (size_t)rb * KG_D + chs * 64;
#pragma unroll
        for (int n = 0; n < 4; ++n) {
            const float rv = relrow[n * 16 + li];
#pragma unroll
            for (int j = 0; j < 4; ++j) {
                const float va = accf[0][n][j];
                const float vp = accf[1][n][j];
                const float vn = accf[2][n][j];
                const float s  = va + rv;
                const float dp = s - vp;
                const float dn = s - vn;
                ps[j] += dp * dp;
                ns[j] += dn * dn;
                sq[j] += va * va + vp * vp + vn * vn + rv * rv;
            }
        }
#pragma unroll
        for (int j = 0; j < 4; ++j)
#pragma unroll
            for (int m = 1; m < 16; m <<= 1) {
                ps[j] += __shfl_xor(ps[j], m);
                ns[j] += __shfl_xor(ns[j], m);
                sq[j] += __shfl_xor(sq[j], m);
            }

        if (li == 0) {
#pragma unroll
            for (int j = 0; j < 4; ++j) {
                const int row = rt * 16 + kq * 4 + j;
                sScr[chs][row][0] = ps[j];
                sScr[chs][row][1] = ns[j];
                sScr[chs][row][2] = sq[j];
            }
        }
        __syncthreads();

        if (tid < 64) {
            float term = 0.f;
            if (tid < KG_TM) {
                const int row = tid;
                const float P = sScr[0][row][0] + sScr[1][row][0];
                const float N = sScr[0][row][1] + sScr[1][row][1];
                const float S = sScr[0][row][2] + sScr[1][row][2];
                const int pg = perm[slot0 + row];
                if (pg >= 0) {
                    const float x = P - N;                          // pos - neg
                    term = fmaxf(x, 0.f) + log1pf(expf(-fabsf(x)))  // softplus
                         + 5e-6f * S;                               // lambda/2 * l2
                }
            }
#pragma unroll
            for (int off = 16; off > 0; off >>= 1) term += __shfl_down(term, off);
            bs = term;
        }
    }

    // ---- fenceless deterministic finalize (atomics only, no threadfence) ----
    if (tid == 0) {
        if (bs != 0.f)
            atomicAdd(acc, (unsigned long long)__double2ll_rn((double)bs * KG_SCALE));
        // wait for the acc atomic to be ack'd at the coherence point before
        // ticking done (a wait, not a cache flush — cheap).
        asm volatile("s_waitcnt vmcnt(0)" ::: "memory");
        if (atomicAdd(done, 1u) == (unsigned)(KG_NGRP - 1)) {
            const unsigned long long tot = atomicAdd(acc, 0ull);
            out[0] = (float)((double)tot * (1.0 / KG_SCALE) * (1.0 / (double)KG_B));
        }
    }
}

extern "C" void kernel_launch(void* const* d_in, const int* in_sizes, int n_in,
                              void* d_out, int out_size, void* d_ws, size_t ws_size,
                              hipStream_t stream) {
    const float* ent = (const float*)d_in[0];
    const float* rel = (const float*)d_in[1];
    const float* M   = (const float*)d_in[2];
    const int*   h   = (const int*)d_in[3];
    const int*   r   = (const int*)d_in[4];
    const int*   pt  = (const int*)d_in[5];
    const int*   nt  = (const int*)d_in[6];

    int*                perm = (int*)d_ws;
    unsigned long long* acc  = (unsigned long long*)((char*)d_ws + WS_ACC_BYTES);
    unsigned int*       done = (unsigned int*)((char*)d_ws + WS_DONE_BYTES);
    unsigned short*     preW = (unsigned short*)((char*)d_ws + WS_PREW_BYTES);
    float*              out  = (float*)d_out;

    kg_sort_prep<<<1 + KG_NR, 1024, 0, stream>>>(r, M, perm, acc, done, preW);
    kg_main     <<<KG_NGRP, 256, 0, stream>>>(ent, rel, preW, h, r, pt, nt, perm,
                                              acc, done, out);
}

// Round 11
// 30.934 us; speedup vs baseline: 1.1702x; 1.1702x over previous
//
#include <hip/hip_runtime.h>
#include <math.h>

#define KG_B    16384
#define KG_D    128
#define KG_NR   24
#define KG_TM   32                        // elements per block
#define KG_BPAD (KG_B + KG_NR * KG_TM)    // 17152
#define KG_NGRP (KG_BPAD / KG_TM)         // 536

// ws layout: int perm[KG_BPAD] | float bsum[KG_NGRP] @ float idx KG_BPAD
//            | ushort preW[24*16384] @ byte 131072
//            | ushort Xp[3*16384*128] @ byte 1048576 (12.6 MB, optional)
#define WS_PREW_BYTES 131072
#define WS_XP_BYTES   1048576
#define WS_XP_SIZE    (3 * KG_B * KG_D * 2)
#define WS_NEED_XP    ((size_t)WS_XP_BYTES + (size_t)WS_XP_SIZE)

typedef __attribute__((ext_vector_type(8))) short bf16x8;
typedef __attribute__((ext_vector_type(4))) float f32x4;

__device__ __forceinline__ unsigned bf16r(float f) {
    return (__float_as_uint(f) + 0x8000u) >> 16;
}
__device__ __forceinline__ unsigned pack2(float lo, float hi) {
    return bf16r(lo) | (bf16r(hi) << 16);
}

// ---- K1: block 0 = fused relation sort; blocks 1..24 = W^T bf16 prep
//      (plain col-major: preW[k][col*128+e] = bf16(W[k][e][col]));
//      blocks 25.. (XP only) = Xp pack: Xp[t3][b][e] = bf16(ent[idx3(b,t3)][e]).
template<int XP>
__global__ __launch_bounds__(1024) void kg_sort_prep(
    const int* __restrict__ r,   const float* __restrict__ M,
    const int* __restrict__ h,   const int* __restrict__ pt,
    const int* __restrict__ nt,  const float* __restrict__ ent,
    int* __restrict__ perm,      unsigned short* __restrict__ preW,
    unsigned short* __restrict__ Xp)
{
    __shared__ int cntw[16][25];
    __shared__ int basew[16][25];
    __shared__ int pbase_s[24];
    __shared__ int cnt_tot[24];
    __shared__ int total_s;
    __shared__ __align__(16) unsigned short sWp[KG_D * KG_D];   // 32 KB (W path)

    const int t = threadIdx.x;

    if (XP && blockIdx.x > KG_NR) {
        // ---------- Xp pack path: one quarter-row (32 dims) per thread ----------
        const int pb = blockIdx.x - 1 - KG_NR;        // 0..191
        const int qr = pb * 1024 + t;                 // 0..196607
        const int t3 = qr >> 16;                      // block-uniform (65536 q/t3)
        const int b  = (qr >> 2) & (KG_B - 1);
        const int qu = qr & 3;
        const int* idxarr = (t3 == 0) ? h : ((t3 == 1) ? pt : nt);
        const int idx = idxarr[b];
        const float* src = ent + (size_t)idx * KG_D + qu * 32;
        float4 f[8];
#pragma unroll
        for (int i = 0; i < 8; ++i) f[i] = ((const float4*)src)[i];
        unsigned u[16];
#pragma unroll
        for (int i = 0; i < 8; ++i) {
            u[2 * i]     = pack2(f[i].x, f[i].y);
            u[2 * i + 1] = pack2(f[i].z, f[i].w);
        }
        uint4* dst = (uint4*)(Xp + ((size_t)t3 * KG_B + b) * KG_D + qu * 32);
#pragma unroll
        for (int i = 0; i < 4; ++i)
            dst[i] = make_uint4(u[4 * i], u[4 * i + 1], u[4 * i + 2], u[4 * i + 3]);
        return;
    }

    if (blockIdx.x != 0) {
        // ---------- W prep path: transpose+pack one 128x128 matrix ----------
        const int k  = blockIdx.x - 1;
        const int e  = t >> 3;              // 0..127
        const int c0 = (t & 7) * 16;
        const float* src = M + ((size_t)k << 14) + (size_t)e * KG_D + c0;
        float4 rw[4];
#pragma unroll
        for (int f = 0; f < 4; ++f) rw[f] = ((const float4*)src)[f];
#pragma unroll
        for (int dc = 0; dc < 16; ++dc) {
            const int col = c0 + dc;
            const float v = ((const float*)&rw[0])[dc];
            sWp[col * KG_D + e] = (unsigned short)bf16r(v);
        }
        __syncthreads();
        uint4* dst = (uint4*)(preW + ((size_t)k << 14));
        const uint4* s4 = (const uint4*)sWp;
        dst[2 * t]     = s4[2 * t];
        dst[2 * t + 1] = s4[2 * t + 1];
        return;
    }

    // ---------- sort path (single block) ----------
    const int w = t >> 6;
    int* cz = &cntw[0][0];
    for (int i = t; i < 16 * 25; i += 1024) cz[i] = 0;
    __syncthreads();

    int kt[16];
#pragma unroll
    for (int j = 0; j < 16; ++j) kt[j] = r[j * 1024 + t];
#pragma unroll
    for (int j = 0; j < 16; ++j) atomicAdd(&cntw[w][kt[j]], 1);
    __syncthreads();

    if (t < 24) {
        int s = 0;
        for (int w2 = 0; w2 < 16; ++w2) { basew[w2][t] = s; s += cntw[w2][t]; }
        cnt_tot[t] = s;
    }
    __syncthreads();
    if (t == 0) {
        int run = 0;
        for (int k = 0; k < 24; ++k) {
            pbase_s[k] = run;
            run += (cnt_tot[k] + (KG_TM - 1)) & ~(KG_TM - 1);
        }
        total_s = run;
    }
    __syncthreads();
    if (t < 24)
        for (int w2 = 0; w2 < 16; ++w2) basew[w2][t] += pbase_s[t];
    for (int i = t; i < 16 * 25; i += 1024) cz[i] = 0;   // reuse cntw as cur
    __syncthreads();

#pragma unroll
    for (int j = 0; j < 16; ++j) {
        const int k = kt[j];
        const int pos = basew[w][k] + atomicAdd(&cntw[w][k], 1);
        perm[pos] = j * 1024 + t;
    }
    __syncthreads();

    if (t < 24) {
        const int e0 = pbase_s[t] + cnt_tot[t];
        const int e1 = pbase_s[t] + ((cnt_tot[t] + (KG_TM - 1)) & ~(KG_TM - 1));
        for (int p = e0; p < e1; ++p) perm[p] = -1;
    }
    for (int i = total_s + t; i < KG_BPAD; i += 1024) perm[i] = -1;
}

// ---- K2: MFMA main. Block = 32 same-relation elements, 4 waves
//      (rt=w&1 rows, chs=w>>1 cols). B direct from L2-resident preW.
//      XP=1: A staged via global_load_lds from pre-packed Xp (slab layout).
//      XP=0: R9 fp32 gather + pack + XOR layout. ----
template<int XP>
__global__ __launch_bounds__(256, 4) void kg_main(
    const float* __restrict__ ent, const float* __restrict__ rel,
    const unsigned short* __restrict__ preW,
    const unsigned short* __restrict__ Xp,
    const int* __restrict__ h,     const int* __restrict__ r,
    const int* __restrict__ pt,    const int* __restrict__ nt,
    const int* __restrict__ perm,  float* __restrict__ bsum)
{
    __shared__ __align__(16) unsigned short sX[3 * KG_TM * KG_D];   // 24 KB
    __shared__ float sScr[2][KG_TM][4];

    const int tid   = threadIdx.x;
    const int slot0 = blockIdx.x * KG_TM;
    const int p0    = perm[slot0];
    if (p0 < 0) {
        if (tid == 0) bsum[blockIdx.x] = 0.f;
        return;
    }
    const int rb = __builtin_amdgcn_readfirstlane(r[p0]);

    const int l  = tid & 63;
    const int wv = tid >> 6;

    if (XP) {
        // slab layout: slab s = t3*16 + o (o = e-octet), 32 rows x 16B each.
        // issue i covers slabs 2i (lanes 0-31) and 2i+1 (lanes 32-63).
        const int pv = perm[slot0 + (l & 31)];
        const int bb = pv < 0 ? p0 : pv;
        const int half = l >> 5;
#pragma unroll
        for (int q = 0; q < 6; ++q) {
            const int i = wv * 6 + q;                 // 0..23
            const int s = 2 * i + half;               // slab 0..47
            const int o = s & 15, t3 = s >> 4;
            const char* src = (const char*)Xp
                + (((size_t)t3 * KG_B + (size_t)bb) << 8) + (o << 4);
            __builtin_amdgcn_global_load_lds(
                (const unsigned int*)src,
                (unsigned int*)((char*)sX + i * 1024), 16, 0, 0);
        }
    } else {
        const int g  = tid >> 3;
        const int e0 = (tid & 7) * 16;
        const int pg = perm[slot0 + g];
        const int bb = pg < 0 ? p0 : pg;
        const int idx3[3] = { h[bb], pt[bb], nt[bb] };
        const int sw = (g & 7) << 3;
#pragma unroll
        for (int t3 = 0; t3 < 3; ++t3) {
            const float* src = ent + (size_t)idx3[t3] * KG_D + e0;
            const float4 f0 = ((const float4*)src)[0];
            const float4 f1 = ((const float4*)src)[1];
            const float4 f2 = ((const float4*)src)[2];
            const float4 f3 = ((const float4*)src)[3];
            uint4 u0, u1;
            u0.x = pack2(f0.x, f0.y); u0.y = pack2(f0.z, f0.w);
            u0.z = pack2(f1.x, f1.y); u0.w = pack2(f1.z, f1.w);
            u1.x = pack2(f2.x, f2.y); u1.y = pack2(f2.z, f2.w);
            u1.z = pack2(f3.x, f3.y); u1.w = pack2(f3.z, f3.w);
            unsigned short* base = sX + t3 * (KG_TM * KG_D) + g * KG_D;
            *(uint4*)(base + ((e0    ) ^ sw)) = u0;
            *(uint4*)(base + ((e0 + 8) ^ sw)) = u1;
        }
    }
    __syncthreads();            // drains vmcnt (global_load_lds) / lds writes

    const int rt  = wv & 1;                // row-tile (16 rows)
    const int chs = wv >> 1;               // column half (64 cols)
    const int li  = l & 15;
    const int kq  = l >> 4;

    const int ar  = rt * 16 + li;
    const int asw = (ar & 7) << 3;

    const unsigned short* __restrict__ preWk = preW + ((size_t)rb << 14);

    f32x4 accf[3][4];
#pragma unroll
    for (int t3 = 0; t3 < 3; ++t3)
#pragma unroll
        for (int n = 0; n < 4; ++n) accf[t3][n] = (f32x4)0.f;

#pragma unroll
    for (int kk = 0; kk < 4; ++kk) {       // K chunks of 32
        bf16x8 af[3];
        if (XP) {
#pragma unroll
            for (int t3 = 0; t3 < 3; ++t3)
                af[t3] = *(const bf16x8*)&sX[(t3 * 16 + kk * 4 + kq) * 256 + ar * 8];
        } else {
            const int e0 = kk * 32 + kq * 8;
#pragma unroll
            for (int t3 = 0; t3 < 3; ++t3)
                af[t3] = *(const bf16x8*)&sX[t3 * (KG_TM * KG_D) + ar * KG_D + (e0 ^ asw)];
        }
        const int e0 = kk * 32 + kq * 8;
#pragma unroll
        for (int n = 0; n < 4; ++n) {
            const int col = chs * 64 + n * 16 + li;
            const bf16x8 bfr = *(const bf16x8*)&preWk[col * KG_D + e0];
            accf[0][n] = __builtin_amdgcn_mfma_f32_16x16x32_bf16(af[0], bfr, accf[0][n], 0, 0, 0);
            accf[1][n] = __builtin_amdgcn_mfma_f32_16x16x32_bf16(af[1], bfr, accf[1][n], 0, 0, 0);
            accf[2][n] = __builtin_amdgcn_mfma_f32_16x16x32_bf16(af[2], bfr, accf[2][n], 0, 0, 0);
        }
    }

    // ---- epilogue: C/D layout col=lane&15, row=(lane>>4)*4+reg ----
    float ps[4] = {0,0,0,0}, ns[4] = {0,0,0,0}, sq[4] = {0,0,0,0};
    const float* relrow = rel + (size_t)rb * KG_D + chs * 64;
#pragma unroll
    for (int n = 0; n < 4; ++n) {
        const float rv = relrow[n * 16 + li];
#pragma unroll
        for (int j = 0; j < 4; ++j) {
            const float va = accf[0][n][j];
            const float vp = accf[1][n][j];
            const float vn = accf[2][n][j];
            const float s  = va + rv;
            const float dp = s - vp;
            const float dn = s - vn;
            ps[j] += dp * dp;
            ns[j] += dn * dn;
            sq[j] += va * va + vp * vp + vn * vn + rv * rv;
        }
    }
#pragma unroll
    for (int j = 0; j < 4; ++j)
#pragma unroll
        for (int m = 1; m < 16; m <<= 1) {
            ps[j] += __shfl_xor(ps[j], m);
            ns[j] += __shfl_xor(ns[j], m);
            sq[j] += __shfl_xor(sq[j], m);
        }

    if (li == 0) {
#pragma unroll
        for (int j = 0; j < 4; ++j) {
            const int row = rt * 16 + kq * 4 + j;
            sScr[chs][row][0] = ps[j];
            sScr[chs][row][1] = ns[j];
            sScr[chs][row][2] = sq[j];
        }
    }
    __syncthreads();

    if (tid < 64) {
        float term = 0.f;
        if (tid < KG_TM) {
            const int row = tid;
            const float P = sScr[0][row][0] + sScr[1][row][0];
            const float N = sScr[0][row][1] + sScr[1][row][1];
            const float S = sScr[0][row][2] + sScr[1][row][2];
            const int pg = perm[slot0 + row];
            if (pg >= 0) {
                const float x = P - N;                            // pos - neg
                term = fmaxf(x, 0.f) + log1pf(expf(-fabsf(x)))    // softplus
                     + 5e-6f * S;                                 // lambda/2 * l2
            }
        }
#pragma unroll
        for (int off = 16; off > 0; off >>= 1) term += __shfl_down(term, off);
        if (tid == 0) bsum[blockIdx.x] = term;
    }
}

// ---- K3: deterministic final reduction over 536 block sums ----
__global__ __launch_bounds__(256) void kg_final(const float* __restrict__ bsum,
                                                float* __restrict__ out) {
    __shared__ float s[256];
    const int t = threadIdx.x;
    float acc = 0.f;
    for (int i = t; i < KG_NGRP; i += 256) acc += bsum[i];
    s[t] = acc;
    __syncthreads();
    for (int off = 128; off > 0; off >>= 1) {
        if (t < off) s[t] += s[t + off];
        __syncthreads();
    }
    if (t == 0) out[0] = s[0] * (1.0f / (float)KG_B);
}

extern "C" void kernel_launch(void* const* d_in, const int* in_sizes, int n_in,
                              void* d_out, int out_size, void* d_ws, size_t ws_size,
                              hipStream_t stream) {
    const float* ent = (const float*)d_in[0];
    const float* rel = (const float*)d_in[1];
    const float* M   = (const float*)d_in[2];
    const int*   h   = (const int*)d_in[3];
    const int*   r   = (const int*)d_in[4];
    const int*   pt  = (const int*)d_in[5];
    const int*   nt  = (const int*)d_in[6];

    int*            perm = (int*)d_ws;
    float*          bsum = (float*)d_ws + KG_BPAD;
    unsigned short* preW = (unsigned short*)((char*)d_ws + WS_PREW_BYTES);
    unsigned short* Xp   = (unsigned short*)((char*)d_ws + WS_XP_BYTES);
    float*          out  = (float*)d_out;

    if (ws_size >= WS_NEED_XP) {
        kg_sort_prep<1><<<1 + KG_NR + 192, 1024, 0, stream>>>(r, M, h, pt, nt, ent,
                                                              perm, preW, Xp);
        kg_main<1>   <<<KG_NGRP, 256, 0, stream>>>(ent, rel, preW, Xp,
                                                   h, r, pt, nt, perm, bsum);
    } else {
        kg_sort_prep<0><<<1 + KG_NR, 1024, 0, stream>>>(r, M, h, pt, nt, ent,
                                                        perm, preW, Xp);
        kg_main<0>   <<<KG_NGRP, 256, 0, stream>>>(ent, rel, preW, Xp,
                                                   h, r, pt, nt, perm, bsum);
    }
    kg_final<<<1, 256, 0, stream>>>(bsum, out);
}

// Round 12
// 28.532 us; speedup vs baseline: 1.2687x; 1.0842x over previous
//
#include <hip/hip_runtime.h>
#include <math.h>

#define KG_B    16384
#define KG_D    128
#define KG_NR   24
#define KG_TM   32                        // elements per block
#define KG_BPAD (KG_B + KG_NR * KG_TM)    // 17152
#define KG_NGRP (KG_BPAD / KG_TM)         // 536

// ws layout: int perm[KG_BPAD] | float bsum[KG_NGRP] | ushort preW[24*16384] @ byte 131072
#define WS_BSUM KG_BPAD
#define WS_PREW_BYTES 131072

typedef __attribute__((ext_vector_type(8))) short bf16x8;
typedef __attribute__((ext_vector_type(4))) float f32x4;

__device__ __forceinline__ unsigned bf16r(float f) {
    return (__float_as_uint(f) + 0x8000u) >> 16;
}
__device__ __forceinline__ unsigned pack2(float lo, float hi) {
    return bf16r(lo) | (bf16r(hi) << 16);
}

// ---- K1: block 0 = fused relation sort; blocks 1..24 = W^T bf16 prep
//      (plain col-major: preW[k][col*128+e] = bf16(W[k][e][col])). ----
__global__ __launch_bounds__(1024) void kg_sort_prep(const int* __restrict__ r,
                                                     const float* __restrict__ M,
                                                     int* __restrict__ perm,
                                                     unsigned short* __restrict__ preW) {
    __shared__ int cntw[16][25];
    __shared__ int basew[16][25];
    __shared__ int pbase_s[24];
    __shared__ int cnt_tot[24];
    __shared__ int total_s;
    __shared__ __align__(16) unsigned short sWp[KG_D * KG_D];   // 32 KB (prep path)

    const int t = threadIdx.x;

    if (blockIdx.x != 0) {
        // ---------- prep path: transpose+pack one 128x128 matrix ----------
        const int k  = blockIdx.x - 1;
        const int e  = t >> 3;              // 0..127
        const int c0 = (t & 7) * 16;
        const float* src = M + ((size_t)k << 14) + (size_t)e * KG_D + c0;
        float4 rw[4];
#pragma unroll
        for (int f = 0; f < 4; ++f) rw[f] = ((const float4*)src)[f];
#pragma unroll
        for (int dc = 0; dc < 16; ++dc) {
            const int col = c0 + dc;
            const float v = ((const float*)&rw[0])[dc];
            sWp[col * KG_D + e] = (unsigned short)bf16r(v);
        }
        __syncthreads();
        uint4* dst = (uint4*)(preW + ((size_t)k << 14));
        const uint4* s4 = (const uint4*)sWp;
        dst[2 * t]     = s4[2 * t];
        dst[2 * t + 1] = s4[2 * t + 1];
        return;
    }

    // ---------- sort path (single block) ----------
    const int w = t >> 6;
    int* cz = &cntw[0][0];
    for (int i = t; i < 16 * 25; i += 1024) cz[i] = 0;
    __syncthreads();

    int kt[16];
#pragma unroll
    for (int j = 0; j < 16; ++j) kt[j] = r[j * 1024 + t];
#pragma unroll
    for (int j = 0; j < 16; ++j) atomicAdd(&cntw[w][kt[j]], 1);
    __syncthreads();

    if (t < 24) {
        int s = 0;
        for (int w2 = 0; w2 < 16; ++w2) { basew[w2][t] = s; s += cntw[w2][t]; }
        cnt_tot[t] = s;
    }
    __syncthreads();
    if (t == 0) {
        int run = 0;
        for (int k = 0; k < 24; ++k) {
            pbase_s[k] = run;
            run += (cnt_tot[k] + (KG_TM - 1)) & ~(KG_TM - 1);
        }
        total_s = run;
    }
    __syncthreads();
    if (t < 24)
        for (int w2 = 0; w2 < 16; ++w2) basew[w2][t] += pbase_s[t];
    for (int i = t; i < 16 * 25; i += 1024) cz[i] = 0;   // reuse cntw as cur
    __syncthreads();

#pragma unroll
    for (int j = 0; j < 16; ++j) {
        const int k = kt[j];
        const int pos = basew[w][k] + atomicAdd(&cntw[w][k], 1);
        perm[pos] = j * 1024 + t;
    }
    __syncthreads();

    if (t < 24) {
        const int e0 = pbase_s[t] + cnt_tot[t];
        const int e1 = pbase_s[t] + ((cnt_tot[t] + (KG_TM - 1)) & ~(KG_TM - 1));
        for (int p = e0; p < e1; ++p) perm[p] = -1;
    }
    for (int i = total_s + t; i < KG_BPAD; i += 1024) perm[i] = -1;
}

// ---- K2: MFMA main. Block = 32 same-relation elements, 4 waves
//      (rt=w&1 rows, chs=w>>1 cols). B pre-loaded to registers BEFORE the
//      staging phase so its L2 latency hides under gather+pack+barrier. ----
__global__ __launch_bounds__(256, 3) void kg_main(
    const float* __restrict__ ent, const float* __restrict__ rel,
    const unsigned short* __restrict__ preW,
    const int* __restrict__ h,     const int* __restrict__ r,
    const int* __restrict__ pt,    const int* __restrict__ nt,
    const int* __restrict__ perm,  float* __restrict__ bsum)
{
    __shared__ __align__(16) unsigned short sX[3 * KG_TM * KG_D];   // 24 KB
    __shared__ float sScr[2][KG_TM][4];

    const int tid   = threadIdx.x;
    const int slot0 = blockIdx.x * KG_TM;
    const int p0    = perm[slot0];
    if (p0 < 0) {
        if (tid == 0) bsum[blockIdx.x] = 0.f;
        return;
    }
    const int rb = __builtin_amdgcn_readfirstlane(r[p0]);

    const int l   = tid & 63;
    const int wv  = tid >> 6;
    const int rt  = wv & 1;                // row-tile (16 rows)
    const int chs = wv >> 1;               // column half (64 cols)
    const int li  = l & 15;
    const int kq  = l >> 4;

    // ---- pre-load ALL 16 B fragments + 4 rel values into registers NOW;
    //      latency overlaps the entire X staging phase below. ----
    const unsigned short* __restrict__ preWk = preW + ((size_t)rb << 14);
    bf16x8 bpre[4][4];
#pragma unroll
    for (int kk = 0; kk < 4; ++kk)
#pragma unroll
        for (int n = 0; n < 4; ++n)
            bpre[kk][n] = *(const bf16x8*)&preWk[(chs * 64 + n * 16 + li) * KG_D
                                                 + kk * 32 + kq * 8];
    const float* relrow = rel + (size_t)rb * KG_D + chs * 64;
    float relv[4];
#pragma unroll
    for (int n = 0; n < 4; ++n) relv[n] = relrow[n * 16 + li];

    // ---- stage X: thread t -> row g=t>>3, 16 dims at e0=(t&7)*16 ----
    {
        const int g  = tid >> 3;
        const int e0 = (tid & 7) * 16;
        const int pg = perm[slot0 + g];
        const int bb = pg < 0 ? p0 : pg;
        const int idx3[3] = { h[bb], pt[bb], nt[bb] };
        const int sw = (g & 7) << 3;
#pragma unroll
        for (int t3 = 0; t3 < 3; ++t3) {
            const float* src = ent + (size_t)idx3[t3] * KG_D + e0;
            const float4 f0 = ((const float4*)src)[0];
            const float4 f1 = ((const float4*)src)[1];
            const float4 f2 = ((const float4*)src)[2];
            const float4 f3 = ((const float4*)src)[3];
            uint4 u0, u1;
            u0.x = pack2(f0.x, f0.y); u0.y = pack2(f0.z, f0.w);
            u0.z = pack2(f1.x, f1.y); u0.w = pack2(f1.z, f1.w);
            u1.x = pack2(f2.x, f2.y); u1.y = pack2(f2.z, f2.w);
            u1.z = pack2(f3.x, f3.y); u1.w = pack2(f3.z, f3.w);
            unsigned short* base = sX + t3 * (KG_TM * KG_D) + g * KG_D;
            *(uint4*)(base + ((e0    ) ^ sw)) = u0;
            *(uint4*)(base + ((e0 + 8) ^ sw)) = u1;
        }
    }
    __syncthreads();

    const int ar  = rt * 16 + li;
    const int asw = (ar & 7) << 3;

    f32x4 accf[3][4];
#pragma unroll
    for (int t3 = 0; t3 < 3; ++t3)
#pragma unroll
        for (int n = 0; n < 4; ++n) accf[t3][n] = (f32x4)0.f;

#pragma unroll
    for (int kk = 0; kk < 4; ++kk) {       // K chunks of 32
        const int e0 = kk * 32 + kq * 8;
        bf16x8 af[3];
#pragma unroll
        for (int t3 = 0; t3 < 3; ++t3)
            af[t3] = *(const bf16x8*)&sX[t3 * (KG_TM * KG_D) + ar * KG_D + (e0 ^ asw)];
#pragma unroll
        for (int n = 0; n < 4; ++n) {
            accf[0][n] = __builtin_amdgcn_mfma_f32_16x16x32_bf16(af[0], bpre[kk][n], accf[0][n], 0, 0, 0);
            accf[1][n] = __builtin_amdgcn_mfma_f32_16x16x32_bf16(af[1], bpre[kk][n], accf[1][n], 0, 0, 0);
            accf[2][n] = __builtin_amdgcn_mfma_f32_16x16x32_bf16(af[2], bpre[kk][n], accf[2][n], 0, 0, 0);
        }
    }

    // ---- epilogue: C/D layout col=lane&15, row=(lane>>4)*4+reg ----
    float ps[4] = {0,0,0,0}, ns[4] = {0,0,0,0}, sq[4] = {0,0,0,0};
#pragma unroll
    for (int n = 0; n < 4; ++n) {
        const float rv = relv[n];
#pragma unroll
        for (int j = 0; j < 4; ++j) {
            const float va = accf[0][n][j];
            const float vp = accf[1][n][j];
            const float vn = accf[2][n][j];
            const float s  = va + rv;
            const float dp = s - vp;
            const float dn = s - vn;
            ps[j] += dp * dp;
            ns[j] += dn * dn;
            sq[j] += va * va + vp * vp + vn * vn + rv * rv;
        }
    }
#pragma unroll
    for (int j = 0; j < 4; ++j)
#pragma unroll
        for (int m = 1; m < 16; m <<= 1) {
            ps[j] += __shfl_xor(ps[j], m);
            ns[j] += __shfl_xor(ns[j], m);
            sq[j] += __shfl_xor(sq[j], m);
        }

    if (li == 0) {
#pragma unroll
        for (int j = 0; j < 4; ++j) {
            const int row = rt * 16 + kq * 4 + j;
            sScr[chs][row][0] = ps[j];
            sScr[chs][row][1] = ns[j];
            sScr[chs][row][2] = sq[j];
        }
    }
    __syncthreads();

    if (tid < 64) {
        float term = 0.f;
        if (tid < KG_TM) {
            const int row = tid;
            const float P = sScr[0][row][0] + sScr[1][row][0];
            const float N = sScr[0][row][1] + sScr[1][row][1];
            const float S = sScr[0][row][2] + sScr[1][row][2];
            const int pg = perm[slot0 + row];
            if (pg >= 0) {
                const float x = P - N;                            // pos - neg
                term = fmaxf(x, 0.f) + log1pf(expf(-fabsf(x)))    // softplus
                     + 5e-6f * S;                                 // lambda/2 * l2
            }
        }
#pragma unroll
        for (int off = 16; off > 0; off >>= 1) term += __shfl_down(term, off);
        if (tid == 0) bsum[blockIdx.x] = term;
    }
}

// ---- K3: deterministic final reduction over 536 block sums ----
__global__ __launch_bounds__(256) void kg_final(const float* __restrict__ bsum,
                                                float* __restrict__ out) {
    __shared__ float s[256];
    const int t = threadIdx.x;
    float acc = 0.f;
    for (int i = t; i < KG_NGRP; i += 256) acc += bsum[i];
    s[t] = acc;
    __syncthreads();
    for (int off = 128; off > 0; off >>= 1) {
        if (t < off) s[t] += s[t + off];
        __syncthreads();
    }
    if (t == 0) out[0] = s[0] * (1.0f / (float)KG_B);
}

extern "C" void kernel_launch(void* const* d_in, const int* in_sizes, int n_in,
                              void* d_out, int out_size, void* d_ws, size_t ws_size,
                              hipStream_t stream) {
    const float* ent = (const float*)d_in[0];
    const float* rel = (const float*)d_in[1];
    const float* M   = (const float*)d_in[2];
    const int*   h   = (const int*)d_in[3];
    const int*   r   = (const int*)d_in[4];
    const int*   pt  = (const int*)d_in[5];
    const int*   nt  = (const int*)d_in[6];

    int*            perm = (int*)d_ws;
    float*          bsum = (float*)d_ws + WS_BSUM;
    unsigned short* preW = (unsigned short*)((char*)d_ws + WS_PREW_BYTES);
    float*          out  = (float*)d_out;

    kg_sort_prep<<<1 + KG_NR, 1024, 0, stream>>>(r, M, perm, preW);
    kg_main     <<<KG_NGRP, 256, 0, stream>>>(ent, rel, preW, h, r, pt, nt, perm, bsum);
    kg_final    <<<1, 256, 0, stream>>>(bsum, out);
}